// Round 16
// baseline (1311.429 us; speedup 1.0000x reference)
//
#include <hip/hip_runtime.h>
#include <cstddef>

constexpr int B = 16, S = 512, E = 128, I = 256, DHm = 64;
constexpr int BS = B * S;

typedef _Float16 half8 __attribute__((ext_vector_type(8)));
typedef _Float16 half4 __attribute__((ext_vector_type(4)));
typedef float f32x4 __attribute__((ext_vector_type(4)));

__device__ __forceinline__ int swz(int row, int col) {
  return (row * 64 + col) ^ ((row & 7) << 3);
}
struct h3s { _Float16 a, b, c; };
__device__ __forceinline__ h3s split3(float x) {
  h3s r;
  r.a = (_Float16)x;
  float t = x - (float)r.a;
  r.b = (_Float16)t;
  t -= (float)r.b;
  r.c = (_Float16)t;
  return r;
}
struct h2s { _Float16 a, b; };
__device__ __forceinline__ h2s split2(float x) {
  h2s r;
  r.a = (_Float16)x;
  r.b = (_Float16)(x - (float)r.a);
  return r;
}

// ---------------- MFMA GEMM: C[M,N] = A[M,K]@W[K,N], fp16 double-split ----------------
template <int K, bool ADD, int FUSE>
__global__ void __launch_bounds__(256) gemm3(const float* __restrict__ A,
                                             const float* __restrict__ W,
                                             const float* __restrict__ lnw,
                                             float* __restrict__ C, int N, int astride) {
  __shared__ _Float16 A1[4096], A2[4096];  // [m][k] swizzled
  __shared__ _Float16 B1[4096], B2[4096];  // [n][k] swizzled (W^T)
  __shared__ float smu[64], srr[64];
  const int n0 = blockIdx.x * 64, m0 = blockIdx.y * 64;
  const int tid = threadIdx.x;
  const int lane = tid & 63, w = tid >> 6;
  const int sband = w * 16;
  const int fr = lane & 15, fg = lane >> 4;

  if constexpr (FUSE == 1) {
    int row = tid >> 2, q = tid & 3;
    const float* ap = A + (size_t)(m0 + row) * astride + q * 32;
    float s1 = 0.f, s2 = 0.f;
#pragma unroll
    for (int i = 0; i < 8; i++) {
      float4 v = *(const float4*)(ap + i * 4);
      s1 += v.x + v.y + v.z + v.w;
      s2 += v.x * v.x + v.y * v.y + v.z * v.z + v.w * v.w;
    }
    s1 += __shfl_xor(s1, 1); s2 += __shfl_xor(s2, 1);
    s1 += __shfl_xor(s1, 2); s2 += __shfl_xor(s2, 2);
    if (q == 0) {
      float mu = s1 * (1.f / 128);
      float var = s2 * (1.f / 128) - mu * mu;
      smu[row] = mu;
      srr[row] = rsqrtf(var + 1e-5f);
    }
  }

  f32x4 acc[4] = {};
#pragma unroll
  for (int k0 = 0; k0 < K; k0 += 64) {
    __syncthreads();
#pragma unroll
    for (int i = 0; i < 4; i++) {
      int lin = tid + i * 256;
      int mm = lin >> 4, kq = (lin & 15) * 4;
      float4 a4;
      if constexpr (FUSE == 2) {
        const float* ap = A + (size_t)(m0 + mm) * astride + k0 + kq;
        float4 g4 = *(const float4*)ap;
        float4 u4 = *(const float4*)(ap + 192);
        a4.x = 0.5f * g4.x * (1.f + erff(g4.x * 0.70710678118f)) * u4.x;
        a4.y = 0.5f * g4.y * (1.f + erff(g4.y * 0.70710678118f)) * u4.y;
        a4.z = 0.5f * g4.z * (1.f + erff(g4.z * 0.70710678118f)) * u4.z;
        a4.w = 0.5f * g4.w * (1.f + erff(g4.w * 0.70710678118f)) * u4.w;
      } else {
        a4 = *(const float4*)(A + (size_t)(m0 + mm) * astride + k0 + kq);
      }
      if constexpr (FUSE == 1) {
        float mu = smu[mm], rr = srr[mm];
        float4 wl = *(const float4*)(lnw + k0 + kq);
        a4.x = (a4.x - mu) * rr * wl.x;
        a4.y = (a4.y - mu) * rr * wl.y;
        a4.z = (a4.z - mu) * rr * wl.z;
        a4.w = (a4.w - mu) * rr * wl.w;
      }
      const float av[4] = {a4.x, a4.y, a4.z, a4.w};
      half4 h1, h2;
#pragma unroll
      for (int j = 0; j < 4; j++) {
        h2s sp = split2(av[j]);
        h1[j] = sp.a; h2[j] = sp.b;
      }
      *(half4*)&A1[swz(mm, kq)] = h1;
      *(half4*)&A2[swz(mm, kq)] = h2;
    }
#pragma unroll
    for (int i = 0; i < 4; i++) {
      int lin = tid + i * 256;
      int kk = lin >> 4, nq = (lin & 15) * 4;
      float4 w4 = *(const float4*)(W + (size_t)(k0 + kk) * N + n0 + nq);
      const float wv[4] = {w4.x, w4.y, w4.z, w4.w};
#pragma unroll
      for (int j = 0; j < 4; j++) {
        h2s sp = split2(wv[j]);
        B1[swz(nq + j, kk)] = sp.a;
        B2[swz(nq + j, kk)] = sp.b;
      }
    }
    __syncthreads();
    half8 a1g0 = *(const half8*)&A1[swz(sband + fr, fg * 8)];
    half8 a1g1 = *(const half8*)&A1[swz(sband + fr, 32 + fg * 8)];
    half8 a2g0 = *(const half8*)&A2[swz(sband + fr, fg * 8)];
    half8 a2g1 = *(const half8*)&A2[swz(sband + fr, 32 + fg * 8)];
#pragma unroll
    for (int ct = 0; ct < 4; ct++) {
      half8 b1g0 = *(const half8*)&B1[swz(ct * 16 + fr, fg * 8)];
      half8 b1g1 = *(const half8*)&B1[swz(ct * 16 + fr, 32 + fg * 8)];
      half8 b2g0 = *(const half8*)&B2[swz(ct * 16 + fr, fg * 8)];
      half8 b2g1 = *(const half8*)&B2[swz(ct * 16 + fr, 32 + fg * 8)];
      acc[ct] = __builtin_amdgcn_mfma_f32_16x16x32_f16(a2g0, b1g0, acc[ct], 0, 0, 0);
      acc[ct] = __builtin_amdgcn_mfma_f32_16x16x32_f16(a1g0, b2g0, acc[ct], 0, 0, 0);
      acc[ct] = __builtin_amdgcn_mfma_f32_16x16x32_f16(a1g0, b1g0, acc[ct], 0, 0, 0);
      acc[ct] = __builtin_amdgcn_mfma_f32_16x16x32_f16(a2g1, b1g1, acc[ct], 0, 0, 0);
      acc[ct] = __builtin_amdgcn_mfma_f32_16x16x32_f16(a1g1, b2g1, acc[ct], 0, 0, 0);
      acc[ct] = __builtin_amdgcn_mfma_f32_16x16x32_f16(a1g1, b1g1, acc[ct], 0, 0, 0);
    }
  }
#pragma unroll
  for (int ct = 0; ct < 4; ct++) {
#pragma unroll
    for (int r = 0; r < 4; r++) {
      int row = m0 + sband + fg * 4 + r;
      int col = n0 + ct * 16 + fr;
      float v = acc[ct][r];
      if (ADD) v += C[(size_t)row * N + col];
      C[(size_t)row * N + col] = v;
    }
  }
}

// ---------------- fused mLSTM middle: conv+silu -> q/k/v(+split3) -> ig/fg gates ----------
__global__ void __launch_bounds__(256) mlstm_mid_kernel(
    const float* __restrict__ UP, const float* __restrict__ conv_W,
    const float* __restrict__ conv_b, const float* __restrict__ qW,
    const float* __restrict__ kW, const float* __restrict__ vW,
    const float* __restrict__ igW, const float* __restrict__ igb,
    const float* __restrict__ fgW, const float* __restrict__ fgb,
    float* __restrict__ XC, float* __restrict__ Q,
    _Float16* __restrict__ K1, _Float16* __restrict__ K2, _Float16* __restrict__ K3,
    _Float16* __restrict__ V1t, _Float16* __restrict__ V2t, _Float16* __restrict__ V3t,
    float* __restrict__ IG, float* __restrict__ FG) {
  __shared__ float xcl[I], xml[I], qkvl[768];
  __shared__ float red[32];
  int r = blockIdx.x, t = threadIdx.x;  // 256 threads
  int s = r & (S - 1);
  const float* xr = UP + (size_t)r * 512 + t;
  float4 w4 = *(const float4*)(conv_W + t * 4);
  float x0 = xr[0];
  float acc = conv_b[t] + x0 * w4.w;
  if (s >= 1) acc += xr[-512] * w4.z;
  if (s >= 2) acc += xr[-1024] * w4.y;
  if (s >= 3) acc += xr[-1536] * w4.x;
  float xc = acc / (1.f + __expf(-acc));
  xcl[t] = xc;
  xml[t] = x0;
  XC[(size_t)r * I + t] = xc;
  __syncthreads();
  int n = t >> 2, o = t & 3;
  const float* qw = qW + n * 16 + o * 4;
  const float* kw = kW + n * 16 + o * 4;
  const float* vw = vW + n * 16 + o * 4;
  float q = 0, k = 0, v = 0;
#pragma unroll
  for (int i = 0; i < 4; i++) {
    float xcv = xcl[n * 4 + i], xmv = xml[n * 4 + i];
    q += xcv * qw[i]; k += xcv * kw[i]; v += xmv * vw[i];
  }
  Q[(size_t)r * I + t] = q;
  {
    h3s sp = split3(k);
    K1[(size_t)r * I + t] = sp.a;
    K2[(size_t)r * I + t] = sp.b;
    K3[(size_t)r * I + t] = sp.c;
  }
  {
    int b = r >> 9, srow = r & (S - 1);
    int h = t >> 6, d = t & 63;
    size_t idx = ((size_t)(b * 4 + h) * 64 + d) * S + srow;
    h3s sp = split3(v);
    V1t[idx] = sp.a;
    V2t[idx] = sp.b;
    V3t[idx] = sp.c;
  }
  qkvl[t] = q; qkvl[256 + t] = k; qkvl[512 + t] = v;
  __syncthreads();
  float ai[4] = {}, af[4] = {};
#pragma unroll
  for (int j = 0; j < 3; j++) {
    int c = t + j * 256;
    float g = qkvl[c];
#pragma unroll
    for (int h = 0; h < 4; h++) {
      ai[h] += g * igW[h * 768 + c];
      af[h] += g * fgW[h * 768 + c];
    }
  }
#pragma unroll
  for (int m = 32; m; m >>= 1)
#pragma unroll
    for (int h = 0; h < 4; h++) {
      ai[h] += __shfl_xor(ai[h], m);
      af[h] += __shfl_xor(af[h], m);
    }
  int wv = t >> 6;
  if ((t & 63) == 0) {
#pragma unroll
    for (int h = 0; h < 4; h++) { red[wv * 8 + h] = ai[h]; red[wv * 8 + 4 + h] = af[h]; }
  }
  __syncthreads();
  if (t < 8) {
    float sum = red[t] + red[8 + t] + red[16 + t] + red[24 + t];
    int b = r >> 9, srow = r & (S - 1);
    int h = t & 3;
    if (t < 4) IG[((size_t)(b * 4 + h)) * S + srow] = sum + igb[h];
    else FG[((size_t)(b * 4 + h)) * S + srow] = sum + fgb[h];
  }
}

// ---- mLSTM attention: causally-balanced pair (s-tiles 7-st' and st'), fp16 triple-split --
__global__ void __launch_bounds__(256) attn_mfma_kernel(
    const float* __restrict__ Q,
    const _Float16* __restrict__ K1g, const _Float16* __restrict__ K2g,
    const _Float16* __restrict__ K3g, const _Float16* __restrict__ V1g,
    const _Float16* __restrict__ V2g, const _Float16* __restrict__ V3g,
    const float* __restrict__ IG, const float* __restrict__ FG,
    const float* __restrict__ XC, const float* __restrict__ UP,
    const float* __restrict__ onw, const float* __restrict__ skip,
    float* __restrict__ HF) {
  __shared__ _Float16 K1[4096], K2[4096], K3[4096];
  __shared__ _Float16 V1[4096], V2[4096], V3[4096];  // [d][t]
  __shared__ _Float16 W1[4096], W2[4096], W3[4096];  // [s][t]
  __shared__ float A_l[512], M_l[512], F_l[512];
  int bid = blockIdx.x;
  int st4 = bid & 3, bh = bid >> 2;
  int b = bh >> 2, h = bh & 3;
  const int stA = 7 - st4, stB = st4;
  const int s0A = stA * 64, s0B = stB * 64;
  int tid = threadIdx.x;
  const float* Qg = Q + ((size_t)b * S) * I + h * DHm;
  const _Float16* K1p = K1g + ((size_t)b * S) * I + h * DHm;
  const _Float16* K2p = K2g + ((size_t)b * S) * I + h * DHm;
  const _Float16* K3p = K3g + ((size_t)b * S) * I + h * DHm;
  const _Float16* V1p = V1g + (size_t)bh * 64 * S;
  const _Float16* V2p = V2g + (size_t)bh * 64 * S;
  const _Float16* V3p = V3g + (size_t)bh * 64 * S;

  const int lane = tid & 63, w = tid >> 6;
  const int sband = w * 16;
  const int fr = lane & 15, fg = lane >> 4;

  // ---- wave 0: decay scan over full S for this bh ----
  if (tid < 64) {
    int l = tid;
    const float* ig = IG + (size_t)bh * S;
    const float* fgp = FG + (size_t)bh * S;
    float lfc[8], av[8], amx[8];
    float cs = 0;
#pragma unroll
    for (int j = 0; j < 8; j++) {
      float f = fgp[l * 8 + j];
      cs += fminf(f, 0.f) - log1pf(__expf(-fabsf(f)));
      lfc[j] = cs;
    }
    float tot = cs, inc = tot;
#pragma unroll
    for (int off = 1; off < 64; off <<= 1) {
      float yv = __shfl_up(inc, off);
      if (l >= off) inc += yv;
    }
    float excl = inc - tot;
    float pm = -1e30f;
#pragma unroll
    for (int j = 0; j < 8; j++) {
      float CSj = excl + lfc[j];
      av[j] = ig[l * 8 + j] - CSj;
      pm = fmaxf(pm, av[j]);
      amx[j] = pm;
      lfc[j] = CSj;
    }
    float incm = pm;
#pragma unroll
    for (int off = 1; off < 64; off <<= 1) {
      float yv = __shfl_up(incm, off);
      if (l >= off) incm = fmaxf(incm, yv);
    }
    float exclm = __shfl_up(incm, 1);
    if (l == 0) exclm = -1e30f;
#pragma unroll
    for (int j = 0; j < 8; j++) {
      float Mj = fmaxf(exclm, amx[j]);
      A_l[l * 8 + j] = av[j];
      M_l[l * 8 + j] = Mj;
      F_l[l * 8 + j] = __expf(-(lfc[j] + Mj));
    }
  }

  // Q fragments for both parts, triple-split
  half8 aq1A[2], aq2A[2], aq3A[2], aq1B[2], aq2B[2], aq3B[2];
  {
    const float* qrowA = Qg + (size_t)(s0A + sband + fr) * I;
    const float* qrowB = Qg + (size_t)(s0B + sband + fr) * I;
#pragma unroll
    for (int c = 0; c < 2; c++) {
      float4 qa = *(const float4*)(qrowA + c * 32 + fg * 8);
      float4 qb = *(const float4*)(qrowA + c * 32 + fg * 8 + 4);
      float qv[8] = {qa.x, qa.y, qa.z, qa.w, qb.x, qb.y, qb.z, qb.w};
#pragma unroll
      for (int j = 0; j < 8; j++) {
        h3s sp = split3(qv[j]);
        aq1A[c][j] = sp.a; aq2A[c][j] = sp.b; aq3A[c][j] = sp.c;
      }
      float4 qc = *(const float4*)(qrowB + c * 32 + fg * 8);
      float4 qd = *(const float4*)(qrowB + c * 32 + fg * 8 + 4);
      float qw[8] = {qc.x, qc.y, qc.z, qc.w, qd.x, qd.y, qd.z, qd.w};
#pragma unroll
      for (int j = 0; j < 8; j++) {
        h3s sp = split3(qw[j]);
        aq1B[c][j] = sp.a; aq2B[c][j] = sp.b; aq3B[c][j] = sp.c;
      }
    }
  }
  __syncthreads();
  float mslA[4], mslB[4];
#pragma unroll
  for (int r = 0; r < 4; r++) {
    mslA[r] = M_l[s0A + sband + fg * 4 + r];
    mslB[r] = M_l[s0B + sband + fg * 4 + r];
  }

  f32x4 haccA[4] = {}, haccB[4] = {};
  float cspA[4] = {}, cspB[4] = {};

  for (int tt = 0; tt <= stA; tt++) {
    int t0 = tt * 64;
    __syncthreads();
#pragma unroll
    for (int i = 0; i < 4; i++) {
      int lin = tid + i * 256;
      int a = lin >> 4, q4 = (lin & 15) * 4;
      size_t koff = (size_t)(t0 + a) * I + q4;
      *(half4*)&K1[swz(a, q4)] = *(const half4*)(K1p + koff);
      *(half4*)&K2[swz(a, q4)] = *(const half4*)(K2p + koff);
      *(half4*)&K3[swz(a, q4)] = *(const half4*)(K3p + koff);
      size_t voff = (size_t)a * S + t0 + q4;
      *(half4*)&V1[swz(a, q4)] = *(const half4*)(V1p + voff);
      *(half4*)&V2[swz(a, q4)] = *(const half4*)(V2p + voff);
      *(half4*)&V3[swz(a, q4)] = *(const half4*)(V3p + voff);
    }
    __syncthreads();
    // ---- part A ----
#pragma unroll
    for (int ct = 0; ct < 4; ct++) {
      f32x4 sacc = {};
#pragma unroll
      for (int c = 0; c < 2; c++) {
        half8 b1 = *(const half8*)&K1[swz(ct * 16 + fr, c * 32 + fg * 8)];
        half8 b2 = *(const half8*)&K2[swz(ct * 16 + fr, c * 32 + fg * 8)];
        half8 b3 = *(const half8*)&K3[swz(ct * 16 + fr, c * 32 + fg * 8)];
        half8 a1 = c ? aq1A[1] : aq1A[0];
        half8 a2 = c ? aq2A[1] : aq2A[0];
        half8 a3 = c ? aq3A[1] : aq3A[0];
        sacc = __builtin_amdgcn_mfma_f32_16x16x32_f16(a3, b1, sacc, 0, 0, 0);
        sacc = __builtin_amdgcn_mfma_f32_16x16x32_f16(a2, b2, sacc, 0, 0, 0);
        sacc = __builtin_amdgcn_mfma_f32_16x16x32_f16(a1, b3, sacc, 0, 0, 0);
        sacc = __builtin_amdgcn_mfma_f32_16x16x32_f16(a2, b1, sacc, 0, 0, 0);
        sacc = __builtin_amdgcn_mfma_f32_16x16x32_f16(a1, b2, sacc, 0, 0, 0);
        sacc = __builtin_amdgcn_mfma_f32_16x16x32_f16(a1, b1, sacc, 0, 0, 0);
      }
      int tg = t0 + ct * 16 + fr;
      float ea = A_l[tg];
#pragma unroll
      for (int r = 0; r < 4; r++) {
        int sl = sband + fg * 4 + r;
        float wv = 0.f;
        if (tg <= s0A + sl) wv = sacc[r] * 0.125f * __expf(ea - mslA[r]);
        cspA[r] += wv;
        h3s sp = split3(wv);
        W1[swz(sl, ct * 16 + fr)] = sp.a;
        W2[swz(sl, ct * 16 + fr)] = sp.b;
        W3[swz(sl, ct * 16 + fr)] = sp.c;
      }
    }
#pragma unroll
    for (int kc = 0; kc < 2; kc++) {
      half8 w1 = *(const half8*)&W1[swz(sband + fr, kc * 32 + fg * 8)];
      half8 w2 = *(const half8*)&W2[swz(sband + fr, kc * 32 + fg * 8)];
      half8 w3 = *(const half8*)&W3[swz(sband + fr, kc * 32 + fg * 8)];
#pragma unroll
      for (int dt = 0; dt < 4; dt++) {
        half8 v1 = *(const half8*)&V1[swz(dt * 16 + fr, kc * 32 + fg * 8)];
        half8 v2 = *(const half8*)&V2[swz(dt * 16 + fr, kc * 32 + fg * 8)];
        half8 v3 = *(const half8*)&V3[swz(dt * 16 + fr, kc * 32 + fg * 8)];
        haccA[dt] = __builtin_amdgcn_mfma_f32_16x16x32_f16(w3, v1, haccA[dt], 0, 0, 0);
        haccA[dt] = __builtin_amdgcn_mfma_f32_16x16x32_f16(w2, v2, haccA[dt], 0, 0, 0);
        haccA[dt] = __builtin_amdgcn_mfma_f32_16x16x32_f16(w1, v3, haccA[dt], 0, 0, 0);
        haccA[dt] = __builtin_amdgcn_mfma_f32_16x16x32_f16(w2, v1, haccA[dt], 0, 0, 0);
        haccA[dt] = __builtin_amdgcn_mfma_f32_16x16x32_f16(w1, v2, haccA[dt], 0, 0, 0);
        haccA[dt] = __builtin_amdgcn_mfma_f32_16x16x32_f16(w1, v1, haccA[dt], 0, 0, 0);
      }
    }
    // ---- part B (tiles subset of A's) ----
    if (tt <= stB) {
#pragma unroll
      for (int ct = 0; ct < 4; ct++) {
        f32x4 sacc = {};
#pragma unroll
        for (int c = 0; c < 2; c++) {
          half8 b1 = *(const half8*)&K1[swz(ct * 16 + fr, c * 32 + fg * 8)];
          half8 b2 = *(const half8*)&K2[swz(ct * 16 + fr, c * 32 + fg * 8)];
          half8 b3 = *(const half8*)&K3[swz(ct * 16 + fr, c * 32 + fg * 8)];
          half8 a1 = c ? aq1B[1] : aq1B[0];
          half8 a2 = c ? aq2B[1] : aq2B[0];
          half8 a3 = c ? aq3B[1] : aq3B[0];
          sacc = __builtin_amdgcn_mfma_f32_16x16x32_f16(a3, b1, sacc, 0, 0, 0);
          sacc = __builtin_amdgcn_mfma_f32_16x16x32_f16(a2, b2, sacc, 0, 0, 0);
          sacc = __builtin_amdgcn_mfma_f32_16x16x32_f16(a1, b3, sacc, 0, 0, 0);
          sacc = __builtin_amdgcn_mfma_f32_16x16x32_f16(a2, b1, sacc, 0, 0, 0);
          sacc = __builtin_amdgcn_mfma_f32_16x16x32_f16(a1, b2, sacc, 0, 0, 0);
          sacc = __builtin_amdgcn_mfma_f32_16x16x32_f16(a1, b1, sacc, 0, 0, 0);
        }
        int tg = t0 + ct * 16 + fr;
        float ea = A_l[tg];
#pragma unroll
        for (int r = 0; r < 4; r++) {
          int sl = sband + fg * 4 + r;
          float wv = 0.f;
          if (tg <= s0B + sl) wv = sacc[r] * 0.125f * __expf(ea - mslB[r]);
          cspB[r] += wv;
          h3s sp = split3(wv);
          W1[swz(sl, ct * 16 + fr)] = sp.a;
          W2[swz(sl, ct * 16 + fr)] = sp.b;
          W3[swz(sl, ct * 16 + fr)] = sp.c;
        }
      }
#pragma unroll
      for (int kc = 0; kc < 2; kc++) {
        half8 w1 = *(const half8*)&W1[swz(sband + fr, kc * 32 + fg * 8)];
        half8 w2 = *(const half8*)&W2[swz(sband + fr, kc * 32 + fg * 8)];
        half8 w3 = *(const half8*)&W3[swz(sband + fr, kc * 32 + fg * 8)];
#pragma unroll
        for (int dt = 0; dt < 4; dt++) {
          half8 v1 = *(const half8*)&V1[swz(dt * 16 + fr, kc * 32 + fg * 8)];
          half8 v2 = *(const half8*)&V2[swz(dt * 16 + fr, kc * 32 + fg * 8)];
          half8 v3 = *(const half8*)&V3[swz(dt * 16 + fr, kc * 32 + fg * 8)];
          haccB[dt] = __builtin_amdgcn_mfma_f32_16x16x32_f16(w3, v1, haccB[dt], 0, 0, 0);
          haccB[dt] = __builtin_amdgcn_mfma_f32_16x16x32_f16(w2, v2, haccB[dt], 0, 0, 0);
          haccB[dt] = __builtin_amdgcn_mfma_f32_16x16x32_f16(w1, v3, haccB[dt], 0, 0, 0);
          haccB[dt] = __builtin_amdgcn_mfma_f32_16x16x32_f16(w2, v1, haccB[dt], 0, 0, 0);
          haccB[dt] = __builtin_amdgcn_mfma_f32_16x16x32_f16(w1, v2, haccB[dt], 0, 0, 0);
          haccB[dt] = __builtin_amdgcn_mfma_f32_16x16x32_f16(w1, v1, haccB[dt], 0, 0, 0);
        }
      }
    }
  }
  // reduce row-sums
#pragma unroll
  for (int m = 1; m < 16; m <<= 1)
#pragma unroll
    for (int r = 0; r < 4; r++) {
      cspA[r] += __shfl_xor(cspA[r], m);
      cspB[r] += __shfl_xor(cspB[r], m);
    }
  float on4[4], sk4[4];
#pragma unroll
  for (int dt = 0; dt < 4; dt++) {
    on4[dt] = onw[h * DHm + dt * 16 + fr];
    sk4[dt] = skip[h * DHm + dt * 16 + fr];
  }
  // epilogue part A then part B
#pragma unroll
  for (int part = 0; part < 2; part++) {
    int s0p = part ? s0B : s0A;
#pragma unroll
    for (int r = 0; r < 4; r++) {
      int sl = sband + fg * 4 + r;
      size_t row = (size_t)b * S + s0p + sl;
      float Fv = F_l[s0p + sl];
      float cspv = part ? cspB[r] : cspA[r];
      float inv = 1.f / (fmaxf(fabsf(cspv), Fv) + 1e-6f);
      float hv[4], s1 = 0.f, s2 = 0.f;
#pragma unroll
      for (int dt = 0; dt < 4; dt++) {
        hv[dt] = (part ? haccB[dt][r] : haccA[dt][r]) * inv;
        s1 += hv[dt];
        s2 += hv[dt] * hv[dt];
      }
#pragma unroll
      for (int m = 1; m < 16; m <<= 1) { s1 += __shfl_xor(s1, m); s2 += __shfl_xor(s2, m); }
      float mu = s1 * (1.f / 64), var = s2 * (1.f / 64) - mu * mu;
      float rr = rsqrtf(var + 1e-5f);
#pragma unroll
      for (int dt = 0; dt < 4; dt++) {
        int col = h * DHm + dt * 16 + fr;
        float xc = XC[row * I + col];
        float zv = UP[row * (2 * I) + I + col];
        float hn = (hv[dt] - mu) * rr * on4[dt];
        HF[row * I + col] = (hn + sk4[dt] * xc) * (zv / (1.f + __expf(-zv)));
      }
    }
  }
}

// ---------------- sLSTM fused pre: LN(4 rows) -> conv+silu -> gate matvecs ----------------
__global__ void __launch_bounds__(512) slstm_pre_kernel(
    const float* __restrict__ X, const float* __restrict__ lnw,
    const float* __restrict__ conv_W, const float* __restrict__ conv_b,
    const float* __restrict__ gW, const float* __restrict__ bias,
    float* __restrict__ GX) {
  __shared__ float xnl[4][128], xcl[128];
  __shared__ float redS[8], redQ[8];
  int r = blockIdx.x, t = threadIdx.x;  // 512 threads
  int s = r & (S - 1);
  int b0 = r - s;
  int rr = t >> 7, cc = t & 127;
  int sr = s - 3 + rr;
  int grow = b0 + (sr > 0 ? sr : 0);
  float x = X[(size_t)grow * E + cc];
  float s1 = x, s2 = x * x;
#pragma unroll
  for (int m = 32; m; m >>= 1) { s1 += __shfl_xor(s1, m); s2 += __shfl_xor(s2, m); }
  int wv = t >> 6;
  if ((t & 63) == 0) { redS[wv] = s1; redQ[wv] = s2; }
  __syncthreads();
  float fs1 = redS[rr * 2] + redS[rr * 2 + 1];
  float fs2 = redQ[rr * 2] + redQ[rr * 2 + 1];
  float mu = fs1 * (1.f / 128);
  float var = fs2 * (1.f / 128) - mu * mu;
  xnl[rr][cc] = (x - mu) * rsqrtf(var + 1e-5f) * lnw[cc];
  __syncthreads();
  if (t < 128) {
    float4 w4 = *(const float4*)(conv_W + t * 4);
    float acc = conv_b[t] + xnl[3][t] * w4.w;
    if (s >= 1) acc += xnl[2][t] * w4.z;
    if (s >= 2) acc += xnl[1][t] * w4.y;
    if (s >= 3) acc += xnl[0][t] * w4.x;
    xcl[t] = acc / (1.f + __expf(-acc));
  }
  __syncthreads();
  int n = t >> 7, g = (t >> 5) & 3, o = t & 31;
  const float* src = (g < 2) ? (xcl + n * 32) : (xnl[3] + n * 32);
  const float* wp = gW + (((size_t)g * 4 + n) * 32 + o) * 32;
  float acc = bias[n * 128 + g * 32 + o];
#pragma unroll
  for (int d = 0; d < 32; d++) acc += src[d] * wp[d];
  GX[(size_t)r * 512 + t] = acc;
}

// ---------------- sLSTM scan: producer-consumer, CH=16, 4-way ILP consumer ----------------
__global__ void __launch_bounds__(128) slstm_scan8(const float* __restrict__ GX,
                                                   const float* __restrict__ R,
                                                   float* __restrict__ HS) {
  constexpr int CH = 16, NCH = S / CH;
  __shared__ float ring[2][CH][128];
  int blk = blockIdx.x;
  int b = blk >> 2, n = blk & 3;
  int tid = threadIdx.x;
  int wv = tid >> 6, l = tid & 63;
  const float* gxp = GX + ((size_t)b * S) * 512 + n * 128;

  float R0[32], R1[32];
  float h_own = 0.f, c = 0.f, nn = 0.f, m = 0.f;
  if (wv == 0) {
#pragma unroll
    for (int d = 0; d < 32; d++) {
      R0[d] = R[((size_t)(n * 32 + d)) * 128 + l];
      R1[d] = R[((size_t)(n * 32 + d)) * 128 + 64 + l];
    }
  } else {
    float v0[CH], v1[CH];
#pragma unroll
    for (int j = 0; j < CH; j++) {
      v0[j] = gxp[(size_t)j * 512 + l];
      v1[j] = gxp[(size_t)j * 512 + 64 + l];
    }
#pragma unroll
    for (int j = 0; j < CH; j++) {
      ring[0][j][l] = v0[j];
      ring[0][j][64 + l] = v1[j];
    }
  }
  __syncthreads();

  for (int ck = 0; ck < NCH; ck++) {
    if (wv == 1) {
      if (ck + 1 < NCH) {
        const float* src = gxp + (size_t)(ck + 1) * CH * 512;
        float v0[CH], v1[CH];
#pragma unroll
        for (int j = 0; j < CH; j++) {
          v0[j] = src[(size_t)j * 512 + l];
          v1[j] = src[(size_t)j * 512 + 64 + l];
        }
        int pb = (ck + 1) & 1;
#pragma unroll
        for (int j = 0; j < CH; j++) {
          ring[pb][j][l] = v0[j];
          ring[pb][j][64 + l] = v1[j];
        }
      }
    } else {
      int cb = ck & 1;
#pragma unroll
      for (int j = 0; j < CH; j++) {
        float g0 = ring[cb][j][l];
        float g1 = ring[cb][j][64 + l];
        float r0p0 = g0, r0p1 = 0.f, r0p2 = 0.f, r0p3 = 0.f;
        float r1p0 = g1, r1p1 = 0.f, r1p2 = 0.f, r1p3 = 0.f;
#pragma unroll
        for (int d = 0; d < 32; d += 4) {
          float hv0 = __shfl(h_own, d);
          float hv1 = __shfl(h_own, d + 1);
          float hv2 = __shfl(h_own, d + 2);
          float hv3 = __shfl(h_own, d + 3);
          r0p0 += hv0 * R0[d];     r1p0 += hv0 * R1[d];
          r0p1 += hv1 * R0[d + 1]; r1p1 += hv1 * R1[d + 1];
          r0p2 += hv2 * R0[d + 2]; r1p2 += hv2 * R1[d + 2];
          r0p3 += hv3 * R0[d + 3]; r1p3 += hv3 * R1[d + 3];
        }
        float raw0 = (r0p0 + r0p1) + (r0p2 + r0p3);
        float raw1 = (r1p0 + r1p1) + (r1p2 + r1p3);
        float fr = __shfl_down(raw0, 32);
        float og = __shfl_down(raw1, 32);
        float ir = raw0, zr = raw1;
        float lsf = fminf(fr, 0.f) - __logf(1.f + __expf(-fabsf(fr)));
        float lfm = m + lsf;
        float mn = fmaxf(ir, lfm);
        float iv = __expf(ir - mn), fv = __expf(lfm - mn);
        float th = 1.f - 2.f / (__expf(2.f * zr) + 1.f);
        c = fv * c + iv * th;
        nn = fv * nn + iv;
        m = mn;
        float hv = (c / nn) / (1.f + __expf(-og));
        h_own = hv;
        int s = ck * CH + j;
        if (l < 32) HS[((size_t)(b * S + s)) * E + n * 32 + l] = hv;
      }
    }
    __syncthreads();
  }
}

// ---------------- sLSTM group-norm (32) + residual add ----------------
__global__ void gnorm_add_kernel(const float* __restrict__ HS, const float* __restrict__ gnw,
                                 float* __restrict__ X) {
  int r = blockIdx.x, t = threadIdx.x;
  float v = HS[(size_t)r * E + t];
  float s1 = v, s2 = v * v;
#pragma unroll
  for (int m = 16; m; m >>= 1) { s1 += __shfl_xor(s1, m, 32); s2 += __shfl_xor(s2, m, 32); }
  float mu = s1 * (1.f / 32), var = s2 * (1.f / 32) - mu * mu;
  X[(size_t)r * E + t] += (v - mu) * rsqrtf(var + 1e-5f) * gnw[t];
}

// ---------------- final LN + FC on last token ----------------
__global__ void head_kernel(const float* __restrict__ X, const float* __restrict__ pw,
                            const float* __restrict__ fcW, const float* __restrict__ fcb,
                            float* __restrict__ out) {
  int b = blockIdx.x, l = threadIdx.x;
  const float* xr = X + ((size_t)(b * S + S - 1)) * E;
  float2 v = *(const float2*)(xr + l * 2);
  float s1 = v.x + v.y, s2 = v.x * v.x + v.y * v.y;
#pragma unroll
  for (int m = 32; m; m >>= 1) { s1 += __shfl_xor(s1, m); s2 += __shfl_xor(s2, m); }
  float mu = s1 * (1.f / E), var = s2 * (1.f / E) - mu * mu;
  float rr = rsqrtf(var + 1e-5f);
  float2 wv = *(const float2*)(pw + l * 2);
  float2 fw = *(const float2*)(fcW + l * 2);
  float acc = (v.x - mu) * rr * wv.x * fw.x + (v.y - mu) * rr * wv.y * fw.y;
#pragma unroll
  for (int m = 32; m; m >>= 1) acc += __shfl_xor(acc, m);
  if (l == 0) out[b] = acc + fcb[0];
}

extern "C" void kernel_launch(void* const* d_in, const int* in_sizes, int n_in, void* d_out,
                              int out_size, void* d_ws, size_t ws_size, hipStream_t stream) {
  const float* in_x = (const float*)d_in[0];
  const float* m_ln_w = (const float*)d_in[1];
  const float* m_up_W = (const float*)d_in[2];
  const float* m_conv_W = (const float*)d_in[3];
  const float* m_conv_b = (const float*)d_in[4];
  const float* m_q_W = (const float*)d_in[5];
  const float* m_k_W = (const float*)d_in[6];
  const float* m_v_W = (const float*)d_in[7];
  const float* m_ig_W = (const float*)d_in[8];
  const float* m_ig_b = (const float*)d_in[9];
  const float* m_fg_W = (const float*)d_in[10];
  const float* m_fg_b = (const float*)d_in[11];
  const float* m_on_w = (const float*)d_in[12];
  const float* m_skip = (const float*)d_in[13];
  const float* m_down_W = (const float*)d_in[14];
  const float* s_ln_w = (const float*)d_in[15];
  const float* s_conv_W = (const float*)d_in[16];
  const float* s_conv_b = (const float*)d_in[17];
  const float* s_gates_W = (const float*)d_in[18];
  const float* s_R = (const float*)d_in[19];
  const float* s_bias = (const float*)d_in[20];
  const float* s_gn_w = (const float*)d_in[21];
  const float* s_ffn_ln_w = (const float*)d_in[22];
  const float* s_ffn_up_W = (const float*)d_in[23];
  const float* s_ffn_down_W = (const float*)d_in[24];
  const float* post_norm_w = (const float*)d_in[25];
  const float* fc_W = (const float*)d_in[26];
  const float* fc_b = (const float*)d_in[27];

  float* ws = (float*)d_ws;
  float* X = ws;                    // 1,048,576 floats
  float* UP = X + 1048576;          // 4,194,304
  float* XC = UP + 4194304;         // 2,097,152
  float* Qb = XC + 2097152;         // 2,097,152
  float* Hb = Qb + 2097152;         // 2,097,152
  float* IGb = Hb + 2097152;        // 32,768
  float* FGb = IGb + 32768;         // 32,768
  _Float16* F16 = (_Float16*)(FGb + 32768);
  _Float16* K1 = F16;               // 2,097,152 halfs each
  _Float16* K2 = K1 + 2097152;
  _Float16* K3 = K2 + 2097152;
  _Float16* V1t = K3 + 2097152;
  _Float16* V2t = V1t + 2097152;
  _Float16* V3t = V2t + 2097152;

  hipMemcpyAsync(X, in_x, (size_t)BS * E * sizeof(float), hipMemcpyDeviceToDevice, stream);

  int mi = 0;
  for (int blk = 0; blk < 7; blk++) {
    if (blk == 1) {
      slstm_pre_kernel<<<BS, 512, 0, stream>>>(X, s_ln_w, s_conv_W, s_conv_b, s_gates_W,
                                               s_bias, UP);
      slstm_scan8<<<64, 128, 0, stream>>>(UP, s_R, Hb);
      gnorm_add_kernel<<<BS, E, 0, stream>>>(Hb, s_gn_w, X);
      gemm3<128, false, 1><<<dim3(6, 128), 256, 0, stream>>>(X, s_ffn_up_W, s_ffn_ln_w, UP,
                                                             384, 128);
      gemm3<192, true, 2><<<dim3(2, 128), 256, 0, stream>>>(UP, s_ffn_down_W, nullptr, X,
                                                            128, 384);
    } else {
      const float* ln_w = m_ln_w + (size_t)mi * E;
      const float* up_W = m_up_W + (size_t)mi * E * 512;
      const float* conv_W = m_conv_W + (size_t)mi * I * 4;
      const float* conv_b = m_conv_b + (size_t)mi * I;
      const float* q_W = m_q_W + (size_t)mi * 1024;
      const float* k_W = m_k_W + (size_t)mi * 1024;
      const float* v_W = m_v_W + (size_t)mi * 1024;
      const float* ig_W = m_ig_W + (size_t)mi * 3072;
      const float* ig_b = m_ig_b + (size_t)mi * 4;
      const float* fg_W = m_fg_W + (size_t)mi * 3072;
      const float* fg_b = m_fg_b + (size_t)mi * 4;
      const float* on_w = m_on_w + (size_t)mi * I;
      const float* skipv = m_skip + (size_t)mi * I;
      const float* down_W = m_down_W + (size_t)mi * I * E;

      gemm3<128, false, 1><<<dim3(8, 128), 256, 0, stream>>>(X, up_W, ln_w, UP, 512, 128);
      mlstm_mid_kernel<<<BS, 256, 0, stream>>>(UP, conv_W, conv_b, q_W, k_W, v_W, ig_W, ig_b,
                                               fg_W, fg_b, XC, Qb, K1, K2, K3, V1t, V2t, V3t,
                                               IGb, FGb);
      attn_mfma_kernel<<<256, 256, 0, stream>>>(Qb, K1, K2, K3, V1t, V2t, V3t, IGb, FGb, XC,
                                                UP, on_w, skipv, Hb);
      gemm3<256, true, 0><<<dim3(2, 128), 256, 0, stream>>>(Hb, down_W, nullptr, X, 128, 256);
      mi++;
    }
  }
  head_kernel<<<B, 64, 0, stream>>>(X, post_norm_w, fc_W, fc_b, (float*)d_out);
}

// Round 17
// 1097.892 us; speedup vs baseline: 1.1945x; 1.1945x over previous
//
#include <hip/hip_runtime.h>
#include <cstddef>

constexpr int B = 16, S = 512, E = 128, I = 256, DHm = 64;
constexpr int BS = B * S;

typedef _Float16 half8 __attribute__((ext_vector_type(8)));
typedef _Float16 half4 __attribute__((ext_vector_type(4)));
typedef float f32x4 __attribute__((ext_vector_type(4)));

__device__ __forceinline__ int swz(int row, int col) {
  return (row * 64 + col) ^ ((row & 7) << 3);
}
struct h2s { _Float16 a, b; };
__device__ __forceinline__ h2s split2(float x) {
  h2s r;
  r.a = (_Float16)x;
  r.b = (_Float16)(x - (float)r.a);
  return r;
}

// ---------------- MFMA GEMM: C[M,N] = A[M,K]@W[K,N], fp16 double-split ----------------
template <int K, bool ADD, int FUSE>
__global__ void __launch_bounds__(256) gemm3(const float* __restrict__ A,
                                             const float* __restrict__ W,
                                             const float* __restrict__ lnw,
                                             float* __restrict__ C, int N, int astride) {
  __shared__ _Float16 A1[4096], A2[4096];  // [m][k] swizzled
  __shared__ _Float16 B1[4096], B2[4096];  // [n][k] swizzled (W^T)
  __shared__ float smu[64], srr[64];
  const int n0 = blockIdx.x * 64, m0 = blockIdx.y * 64;
  const int tid = threadIdx.x;
  const int lane = tid & 63, w = tid >> 6;
  const int sband = w * 16;
  const int fr = lane & 15, fg = lane >> 4;

  if constexpr (FUSE == 1) {
    int row = tid >> 2, q = tid & 3;
    const float* ap = A + (size_t)(m0 + row) * astride + q * 32;
    float s1 = 0.f, s2 = 0.f;
#pragma unroll
    for (int i = 0; i < 8; i++) {
      float4 v = *(const float4*)(ap + i * 4);
      s1 += v.x + v.y + v.z + v.w;
      s2 += v.x * v.x + v.y * v.y + v.z * v.z + v.w * v.w;
    }
    s1 += __shfl_xor(s1, 1); s2 += __shfl_xor(s2, 1);
    s1 += __shfl_xor(s1, 2); s2 += __shfl_xor(s2, 2);
    if (q == 0) {
      float mu = s1 * (1.f / 128);
      float var = s2 * (1.f / 128) - mu * mu;
      smu[row] = mu;
      srr[row] = rsqrtf(var + 1e-5f);
    }
  }

  f32x4 acc[4] = {};
#pragma unroll
  for (int k0 = 0; k0 < K; k0 += 64) {
    __syncthreads();
#pragma unroll
    for (int i = 0; i < 4; i++) {
      int lin = tid + i * 256;
      int mm = lin >> 4, kq = (lin & 15) * 4;
      float4 a4;
      if constexpr (FUSE == 2) {
        const float* ap = A + (size_t)(m0 + mm) * astride + k0 + kq;
        float4 g4 = *(const float4*)ap;
        float4 u4 = *(const float4*)(ap + 192);
        a4.x = 0.5f * g4.x * (1.f + erff(g4.x * 0.70710678118f)) * u4.x;
        a4.y = 0.5f * g4.y * (1.f + erff(g4.y * 0.70710678118f)) * u4.y;
        a4.z = 0.5f * g4.z * (1.f + erff(g4.z * 0.70710678118f)) * u4.z;
        a4.w = 0.5f * g4.w * (1.f + erff(g4.w * 0.70710678118f)) * u4.w;
      } else {
        a4 = *(const float4*)(A + (size_t)(m0 + mm) * astride + k0 + kq);
      }
      if constexpr (FUSE == 1) {
        float mu = smu[mm], rr = srr[mm];
        float4 wl = *(const float4*)(lnw + k0 + kq);
        a4.x = (a4.x - mu) * rr * wl.x;
        a4.y = (a4.y - mu) * rr * wl.y;
        a4.z = (a4.z - mu) * rr * wl.z;
        a4.w = (a4.w - mu) * rr * wl.w;
      }
      const float av[4] = {a4.x, a4.y, a4.z, a4.w};
      half4 h1, h2;
#pragma unroll
      for (int j = 0; j < 4; j++) {
        h2s sp = split2(av[j]);
        h1[j] = sp.a; h2[j] = sp.b;
      }
      *(half4*)&A1[swz(mm, kq)] = h1;
      *(half4*)&A2[swz(mm, kq)] = h2;
    }
#pragma unroll
    for (int i = 0; i < 4; i++) {
      int lin = tid + i * 256;
      int kk = lin >> 4, nq = (lin & 15) * 4;
      float4 w4 = *(const float4*)(W + (size_t)(k0 + kk) * N + n0 + nq);
      const float wv[4] = {w4.x, w4.y, w4.z, w4.w};
#pragma unroll
      for (int j = 0; j < 4; j++) {
        h2s sp = split2(wv[j]);
        B1[swz(nq + j, kk)] = sp.a;
        B2[swz(nq + j, kk)] = sp.b;
      }
    }
    __syncthreads();
    half8 a1g0 = *(const half8*)&A1[swz(sband + fr, fg * 8)];
    half8 a1g1 = *(const half8*)&A1[swz(sband + fr, 32 + fg * 8)];
    half8 a2g0 = *(const half8*)&A2[swz(sband + fr, fg * 8)];
    half8 a2g1 = *(const half8*)&A2[swz(sband + fr, 32 + fg * 8)];
#pragma unroll
    for (int ct = 0; ct < 4; ct++) {
      half8 b1g0 = *(const half8*)&B1[swz(ct * 16 + fr, fg * 8)];
      half8 b1g1 = *(const half8*)&B1[swz(ct * 16 + fr, 32 + fg * 8)];
      half8 b2g0 = *(const half8*)&B2[swz(ct * 16 + fr, fg * 8)];
      half8 b2g1 = *(const half8*)&B2[swz(ct * 16 + fr, 32 + fg * 8)];
      acc[ct] = __builtin_amdgcn_mfma_f32_16x16x32_f16(a2g0, b1g0, acc[ct], 0, 0, 0);
      acc[ct] = __builtin_amdgcn_mfma_f32_16x16x32_f16(a1g0, b2g0, acc[ct], 0, 0, 0);
      acc[ct] = __builtin_amdgcn_mfma_f32_16x16x32_f16(a1g0, b1g0, acc[ct], 0, 0, 0);
      acc[ct] = __builtin_amdgcn_mfma_f32_16x16x32_f16(a2g1, b1g1, acc[ct], 0, 0, 0);
      acc[ct] = __builtin_amdgcn_mfma_f32_16x16x32_f16(a1g1, b2g1, acc[ct], 0, 0, 0);
      acc[ct] = __builtin_amdgcn_mfma_f32_16x16x32_f16(a1g1, b1g1, acc[ct], 0, 0, 0);
    }
  }
#pragma unroll
  for (int ct = 0; ct < 4; ct++) {
#pragma unroll
    for (int r = 0; r < 4; r++) {
      int row = m0 + sband + fg * 4 + r;
      int col = n0 + ct * 16 + fr;
      float v = acc[ct][r];
      if (ADD) v += C[(size_t)row * N + col];
      C[(size_t)row * N + col] = v;
    }
  }
}

// ---------------- fused mLSTM middle: conv+silu -> q/k/v(+split2) -> ig/fg gates ----------
__global__ void __launch_bounds__(256) mlstm_mid_kernel(
    const float* __restrict__ UP, const float* __restrict__ conv_W,
    const float* __restrict__ conv_b, const float* __restrict__ qW,
    const float* __restrict__ kW, const float* __restrict__ vW,
    const float* __restrict__ igW, const float* __restrict__ igb,
    const float* __restrict__ fgW, const float* __restrict__ fgb,
    float* __restrict__ XC, float* __restrict__ Q,
    _Float16* __restrict__ K1, _Float16* __restrict__ K2,
    _Float16* __restrict__ V1t, _Float16* __restrict__ V2t,
    float* __restrict__ IG, float* __restrict__ FG) {
  __shared__ float xcl[I], xml[I], qkvl[768];
  __shared__ float red[32];
  int r = blockIdx.x, t = threadIdx.x;  // 256 threads
  int s = r & (S - 1);
  const float* xr = UP + (size_t)r * 512 + t;
  float4 w4 = *(const float4*)(conv_W + t * 4);
  float x0 = xr[0];
  float acc = conv_b[t] + x0 * w4.w;
  if (s >= 1) acc += xr[-512] * w4.z;
  if (s >= 2) acc += xr[-1024] * w4.y;
  if (s >= 3) acc += xr[-1536] * w4.x;
  float xc = acc / (1.f + __expf(-acc));
  xcl[t] = xc;
  xml[t] = x0;
  XC[(size_t)r * I + t] = xc;
  __syncthreads();
  int n = t >> 2, o = t & 3;
  const float* qw = qW + n * 16 + o * 4;
  const float* kw = kW + n * 16 + o * 4;
  const float* vw = vW + n * 16 + o * 4;
  float q = 0, k = 0, v = 0;
#pragma unroll
  for (int i = 0; i < 4; i++) {
    float xcv = xcl[n * 4 + i], xmv = xml[n * 4 + i];
    q += xcv * qw[i]; k += xcv * kw[i]; v += xmv * vw[i];
  }
  Q[(size_t)r * I + t] = q;
  {
    h2s sp = split2(k);
    K1[(size_t)r * I + t] = sp.a;
    K2[(size_t)r * I + t] = sp.b;
  }
  {
    int b = r >> 9, srow = r & (S - 1);
    int h = t >> 6, d = t & 63;
    size_t idx = ((size_t)(b * 4 + h) * 64 + d) * S + srow;
    h2s sp = split2(v);
    V1t[idx] = sp.a;
    V2t[idx] = sp.b;
  }
  qkvl[t] = q; qkvl[256 + t] = k; qkvl[512 + t] = v;
  __syncthreads();
  float ai[4] = {}, af[4] = {};
#pragma unroll
  for (int j = 0; j < 3; j++) {
    int c = t + j * 256;
    float g = qkvl[c];
#pragma unroll
    for (int h = 0; h < 4; h++) {
      ai[h] += g * igW[h * 768 + c];
      af[h] += g * fgW[h * 768 + c];
    }
  }
#pragma unroll
  for (int m = 32; m; m >>= 1)
#pragma unroll
    for (int h = 0; h < 4; h++) {
      ai[h] += __shfl_xor(ai[h], m);
      af[h] += __shfl_xor(af[h], m);
    }
  int wv = t >> 6;
  if ((t & 63) == 0) {
#pragma unroll
    for (int h = 0; h < 4; h++) { red[wv * 8 + h] = ai[h]; red[wv * 8 + 4 + h] = af[h]; }
  }
  __syncthreads();
  if (t < 8) {
    float sum = red[t] + red[8 + t] + red[16 + t] + red[24 + t];
    int b = r >> 9, srow = r & (S - 1);
    int h = t & 3;
    if (t < 4) IG[((size_t)(b * 4 + h)) * S + srow] = sum + igb[h];
    else FG[((size_t)(b * 4 + h)) * S + srow] = sum + fgb[h];
  }
}

// ---------------- mLSTM attention: fp16 MFMA double-split, pre-split K/V, in-block decay --
__global__ void __launch_bounds__(256) attn_mfma_kernel(
    const float* __restrict__ Q,
    const _Float16* __restrict__ K1g, const _Float16* __restrict__ K2g,
    const _Float16* __restrict__ V1g, const _Float16* __restrict__ V2g,
    const float* __restrict__ IG, const float* __restrict__ FG,
    const float* __restrict__ XC, const float* __restrict__ UP,
    const float* __restrict__ onw, const float* __restrict__ skip,
    float* __restrict__ HF) {
  __shared__ _Float16 K1[4096], K2[4096];
  __shared__ _Float16 V1[4096], V2[4096];  // [d][t]
  __shared__ _Float16 W1[4096], W2[4096];  // [s][t]
  __shared__ float A_l[512], M_l[512], F_l[512];
  int bid = blockIdx.x;
  int st = bid & 7, bh = bid >> 3;
  int b = bh >> 2, h = bh & 3;
  int s0 = st * 64;
  int tid = threadIdx.x;
  const float* Qg = Q + ((size_t)b * S) * I + h * DHm;
  const _Float16* K1p = K1g + ((size_t)b * S) * I + h * DHm;
  const _Float16* K2p = K2g + ((size_t)b * S) * I + h * DHm;
  const _Float16* V1p = V1g + (size_t)bh * 64 * S;
  const _Float16* V2p = V2g + (size_t)bh * 64 * S;

  const int lane = tid & 63, w = tid >> 6;
  const int sband = w * 16;
  const int fr = lane & 15, fg = lane >> 4;

  // ---- wave 0: decay scan over full S for this bh ----
  if (tid < 64) {
    int l = tid;
    const float* ig = IG + (size_t)bh * S;
    const float* fgp = FG + (size_t)bh * S;
    float lfc[8], av[8], amx[8];
    float cs = 0;
#pragma unroll
    for (int j = 0; j < 8; j++) {
      float f = fgp[l * 8 + j];
      cs += fminf(f, 0.f) - log1pf(__expf(-fabsf(f)));
      lfc[j] = cs;
    }
    float tot = cs, inc = tot;
#pragma unroll
    for (int off = 1; off < 64; off <<= 1) {
      float yv = __shfl_up(inc, off);
      if (l >= off) inc += yv;
    }
    float excl = inc - tot;
    float pm = -1e30f;
#pragma unroll
    for (int j = 0; j < 8; j++) {
      float CSj = excl + lfc[j];
      av[j] = ig[l * 8 + j] - CSj;
      pm = fmaxf(pm, av[j]);
      amx[j] = pm;
      lfc[j] = CSj;
    }
    float incm = pm;
#pragma unroll
    for (int off = 1; off < 64; off <<= 1) {
      float yv = __shfl_up(incm, off);
      if (l >= off) incm = fmaxf(incm, yv);
    }
    float exclm = __shfl_up(incm, 1);
    if (l == 0) exclm = -1e30f;
#pragma unroll
    for (int j = 0; j < 8; j++) {
      float Mj = fmaxf(exclm, amx[j]);
      A_l[l * 8 + j] = av[j];
      M_l[l * 8 + j] = Mj;
      F_l[l * 8 + j] = __expf(-(lfc[j] + Mj));
    }
  }

  // Q fragments in registers, double-split
  half8 aq1[2], aq2[2];
  {
    const float* qrow = Qg + (size_t)(s0 + sband + fr) * I;
#pragma unroll
    for (int c = 0; c < 2; c++) {
      float4 qa = *(const float4*)(qrow + c * 32 + fg * 8);
      float4 qb = *(const float4*)(qrow + c * 32 + fg * 8 + 4);
      float qv[8] = {qa.x, qa.y, qa.z, qa.w, qb.x, qb.y, qb.z, qb.w};
#pragma unroll
      for (int j = 0; j < 8; j++) {
        h2s sp = split2(qv[j]);
        aq1[c][j] = sp.a; aq2[c][j] = sp.b;
      }
    }
  }
  __syncthreads();
  float msl[4];
#pragma unroll
  for (int r = 0; r < 4; r++) msl[r] = M_l[s0 + sband + fg * 4 + r];

  f32x4 hacc[4] = {};
  float csp[4] = {};

  for (int tt = 0; tt <= st; tt++) {
    int t0 = tt * 64;
    __syncthreads();
#pragma unroll
    for (int i = 0; i < 4; i++) {
      int lin = tid + i * 256;
      int a = lin >> 4, q4 = (lin & 15) * 4;
      size_t koff = (size_t)(t0 + a) * I + q4;
      *(half4*)&K1[swz(a, q4)] = *(const half4*)(K1p + koff);
      *(half4*)&K2[swz(a, q4)] = *(const half4*)(K2p + koff);
      size_t voff = (size_t)a * S + t0 + q4;
      *(half4*)&V1[swz(a, q4)] = *(const half4*)(V1p + voff);
      *(half4*)&V2[swz(a, q4)] = *(const half4*)(V2p + voff);
    }
    __syncthreads();
    // QK^T with double-split
#pragma unroll
    for (int ct = 0; ct < 4; ct++) {
      f32x4 sacc = {};
#pragma unroll
      for (int c = 0; c < 2; c++) {
        half8 b1 = *(const half8*)&K1[swz(ct * 16 + fr, c * 32 + fg * 8)];
        half8 b2 = *(const half8*)&K2[swz(ct * 16 + fr, c * 32 + fg * 8)];
        sacc = __builtin_amdgcn_mfma_f32_16x16x32_f16(aq2[c], b1, sacc, 0, 0, 0);
        sacc = __builtin_amdgcn_mfma_f32_16x16x32_f16(aq1[c], b2, sacc, 0, 0, 0);
        sacc = __builtin_amdgcn_mfma_f32_16x16x32_f16(aq1[c], b1, sacc, 0, 0, 0);
      }
      int tg = t0 + ct * 16 + fr;
      float ea = A_l[tg];
#pragma unroll
      for (int r = 0; r < 4; r++) {
        int sl = sband + fg * 4 + r;
        float wv = 0.f;
        if (tg <= s0 + sl) wv = sacc[r] * 0.125f * __expf(ea - msl[r]);
        csp[r] += wv;
        h2s sp = split2(wv);
        W1[swz(sl, ct * 16 + fr)] = sp.a;
        W2[swz(sl, ct * 16 + fr)] = sp.b;
      }
    }
    // PV with double-split
#pragma unroll
    for (int kc = 0; kc < 2; kc++) {
      half8 w1 = *(const half8*)&W1[swz(sband + fr, kc * 32 + fg * 8)];
      half8 w2 = *(const half8*)&W2[swz(sband + fr, kc * 32 + fg * 8)];
#pragma unroll
      for (int dt = 0; dt < 4; dt++) {
        half8 v1 = *(const half8*)&V1[swz(dt * 16 + fr, kc * 32 + fg * 8)];
        half8 v2 = *(const half8*)&V2[swz(dt * 16 + fr, kc * 32 + fg * 8)];
        hacc[dt] = __builtin_amdgcn_mfma_f32_16x16x32_f16(w2, v1, hacc[dt], 0, 0, 0);
        hacc[dt] = __builtin_amdgcn_mfma_f32_16x16x32_f16(w1, v2, hacc[dt], 0, 0, 0);
        hacc[dt] = __builtin_amdgcn_mfma_f32_16x16x32_f16(w1, v1, hacc[dt], 0, 0, 0);
      }
    }
  }
#pragma unroll
  for (int m = 1; m < 16; m <<= 1)
#pragma unroll
    for (int r = 0; r < 4; r++) csp[r] += __shfl_xor(csp[r], m);
  float on4[4], sk4[4];
#pragma unroll
  for (int dt = 0; dt < 4; dt++) {
    on4[dt] = onw[h * DHm + dt * 16 + fr];
    sk4[dt] = skip[h * DHm + dt * 16 + fr];
  }
#pragma unroll
  for (int r = 0; r < 4; r++) {
    int sl = sband + fg * 4 + r;
    size_t row = (size_t)b * S + s0 + sl;
    float Fv = F_l[s0 + sl];
    float inv = 1.f / (fmaxf(fabsf(csp[r]), Fv) + 1e-6f);
    float hv[4], s1 = 0.f, s2 = 0.f;
#pragma unroll
    for (int dt = 0; dt < 4; dt++) {
      hv[dt] = hacc[dt][r] * inv;
      s1 += hv[dt];
      s2 += hv[dt] * hv[dt];
    }
#pragma unroll
    for (int m = 1; m < 16; m <<= 1) { s1 += __shfl_xor(s1, m); s2 += __shfl_xor(s2, m); }
    float mu = s1 * (1.f / 64), var = s2 * (1.f / 64) - mu * mu;
    float rr = rsqrtf(var + 1e-5f);
#pragma unroll
    for (int dt = 0; dt < 4; dt++) {
      int col = h * DHm + dt * 16 + fr;
      float xc = XC[row * I + col];
      float zv = UP[row * (2 * I) + I + col];
      float hn = (hv[dt] - mu) * rr * on4[dt];
      HF[row * I + col] = (hn + sk4[dt] * xc) * (zv / (1.f + __expf(-zv)));
    }
  }
}

// ---------------- sLSTM fused pre: LN(4 rows) -> conv+silu -> gate matvecs ----------------
__global__ void __launch_bounds__(512) slstm_pre_kernel(
    const float* __restrict__ X, const float* __restrict__ lnw,
    const float* __restrict__ conv_W, const float* __restrict__ conv_b,
    const float* __restrict__ gW, const float* __restrict__ bias,
    float* __restrict__ GX) {
  __shared__ float xnl[4][128], xcl[128];
  __shared__ float redS[8], redQ[8];
  int r = blockIdx.x, t = threadIdx.x;  // 512 threads
  int s = r & (S - 1);
  int b0 = r - s;
  int rr = t >> 7, cc = t & 127;
  int sr = s - 3 + rr;
  int grow = b0 + (sr > 0 ? sr : 0);
  float x = X[(size_t)grow * E + cc];
  float s1 = x, s2 = x * x;
#pragma unroll
  for (int m = 32; m; m >>= 1) { s1 += __shfl_xor(s1, m); s2 += __shfl_xor(s2, m); }
  int wv = t >> 6;
  if ((t & 63) == 0) { redS[wv] = s1; redQ[wv] = s2; }
  __syncthreads();
  float fs1 = redS[rr * 2] + redS[rr * 2 + 1];
  float fs2 = redQ[rr * 2] + redQ[rr * 2 + 1];
  float mu = fs1 * (1.f / 128);
  float var = fs2 * (1.f / 128) - mu * mu;
  xnl[rr][cc] = (x - mu) * rsqrtf(var + 1e-5f) * lnw[cc];
  __syncthreads();
  if (t < 128) {
    float4 w4 = *(const float4*)(conv_W + t * 4);
    float acc = conv_b[t] + xnl[3][t] * w4.w;
    if (s >= 1) acc += xnl[2][t] * w4.z;
    if (s >= 2) acc += xnl[1][t] * w4.y;
    if (s >= 3) acc += xnl[0][t] * w4.x;
    xcl[t] = acc / (1.f + __expf(-acc));
  }
  __syncthreads();
  int n = t >> 7, g = (t >> 5) & 3, o = t & 31;
  const float* src = (g < 2) ? (xcl + n * 32) : (xnl[3] + n * 32);
  const float* wp = gW + (((size_t)g * 4 + n) * 32 + o) * 32;
  float acc = bias[n * 128 + g * 32 + o];
#pragma unroll
  for (int d = 0; d < 32; d++) acc += src[d] * wp[d];
  GX[(size_t)r * 512 + t] = acc;
}

// ---- sLSTM scan: producer-consumer, CH=16, 4-way ILP + fused group-norm/residual ----
__global__ void __launch_bounds__(128) slstm_scan9(const float* __restrict__ GX,
                                                   const float* __restrict__ R,
                                                   const float* __restrict__ gnw,
                                                   float* __restrict__ X) {
  constexpr int CH = 16, NCH = S / CH;
  __shared__ float ring[2][CH][128];
  int blk = blockIdx.x;
  int b = blk >> 2, n = blk & 3;
  int tid = threadIdx.x;
  int wv = tid >> 6, l = tid & 63;
  const float* gxp = GX + ((size_t)b * S) * 512 + n * 128;

  float R0[32], R1[32];
  float h_own = 0.f, c = 0.f, nn = 0.f, m = 0.f;
  float gnl = 0.f;
  if (wv == 0) {
#pragma unroll
    for (int d = 0; d < 32; d++) {
      R0[d] = R[((size_t)(n * 32 + d)) * 128 + l];
      R1[d] = R[((size_t)(n * 32 + d)) * 128 + 64 + l];
    }
    if (l < 32) gnl = gnw[n * 32 + l];
  } else {
    float v0[CH], v1[CH];
#pragma unroll
    for (int j = 0; j < CH; j++) {
      v0[j] = gxp[(size_t)j * 512 + l];
      v1[j] = gxp[(size_t)j * 512 + 64 + l];
    }
#pragma unroll
    for (int j = 0; j < CH; j++) {
      ring[0][j][l] = v0[j];
      ring[0][j][64 + l] = v1[j];
    }
  }
  __syncthreads();

  for (int ck = 0; ck < NCH; ck++) {
    if (wv == 1) {
      if (ck + 1 < NCH) {
        const float* src = gxp + (size_t)(ck + 1) * CH * 512;
        float v0[CH], v1[CH];
#pragma unroll
        for (int j = 0; j < CH; j++) {
          v0[j] = src[(size_t)j * 512 + l];
          v1[j] = src[(size_t)j * 512 + 64 + l];
        }
        int pb = (ck + 1) & 1;
#pragma unroll
        for (int j = 0; j < CH; j++) {
          ring[pb][j][l] = v0[j];
          ring[pb][j][64 + l] = v1[j];
        }
      }
    } else {
      int cb = ck & 1;
#pragma unroll
      for (int j = 0; j < CH; j++) {
        float g0 = ring[cb][j][l];
        float g1 = ring[cb][j][64 + l];
        float r0p0 = g0, r0p1 = 0.f, r0p2 = 0.f, r0p3 = 0.f;
        float r1p0 = g1, r1p1 = 0.f, r1p2 = 0.f, r1p3 = 0.f;
#pragma unroll
        for (int d = 0; d < 32; d += 4) {
          float hv0 = __shfl(h_own, d);
          float hv1 = __shfl(h_own, d + 1);
          float hv2 = __shfl(h_own, d + 2);
          float hv3 = __shfl(h_own, d + 3);
          r0p0 += hv0 * R0[d];     r1p0 += hv0 * R1[d];
          r0p1 += hv1 * R0[d + 1]; r1p1 += hv1 * R1[d + 1];
          r0p2 += hv2 * R0[d + 2]; r1p2 += hv2 * R1[d + 2];
          r0p3 += hv3 * R0[d + 3]; r1p3 += hv3 * R1[d + 3];
        }
        float raw0 = (r0p0 + r0p1) + (r0p2 + r0p3);
        float raw1 = (r1p0 + r1p1) + (r1p2 + r1p3);
        float fr = __shfl_down(raw0, 32);
        float og = __shfl_down(raw1, 32);
        float ir = raw0, zr = raw1;
        float lsf = fminf(fr, 0.f) - __logf(1.f + __expf(-fabsf(fr)));
        float lfm = m + lsf;
        float mn = fmaxf(ir, lfm);
        float iv = __expf(ir - mn), fv = __expf(lfm - mn);
        float th = 1.f - 2.f / (__expf(2.f * zr) + 1.f);
        c = fv * c + iv * th;
        nn = fv * nn + iv;
        m = mn;
        float hv = (c / nn) / (1.f + __expf(-og));
        h_own = hv;
        // fused group-norm(32) + residual add (lanes 0-31 hold the group)
        float s1 = hv, s2 = hv * hv;
#pragma unroll
        for (int mm2 = 16; mm2; mm2 >>= 1) {
          s1 += __shfl_xor(s1, mm2, 32);
          s2 += __shfl_xor(s2, mm2, 32);
        }
        float mu = s1 * (1.f / 32), var = s2 * (1.f / 32) - mu * mu;
        float hn = (hv - mu) * rsqrtf(var + 1e-5f) * gnl;
        int s = ck * CH + j;
        if (l < 32) X[((size_t)(b * S + s)) * E + n * 32 + l] += hn;
      }
    }
    __syncthreads();
  }
}

// ---------------- final LN + FC on last token ----------------
__global__ void head_kernel(const float* __restrict__ X, const float* __restrict__ pw,
                            const float* __restrict__ fcW, const float* __restrict__ fcb,
                            float* __restrict__ out) {
  int b = blockIdx.x, l = threadIdx.x;
  const float* xr = X + ((size_t)(b * S + S - 1)) * E;
  float2 v = *(const float2*)(xr + l * 2);
  float s1 = v.x + v.y, s2 = v.x * v.x + v.y * v.y;
#pragma unroll
  for (int m = 32; m; m >>= 1) { s1 += __shfl_xor(s1, m); s2 += __shfl_xor(s2, m); }
  float mu = s1 * (1.f / E), var = s2 * (1.f / E) - mu * mu;
  float rr = rsqrtf(var + 1e-5f);
  float2 wv = *(const float2*)(pw + l * 2);
  float2 fw = *(const float2*)(fcW + l * 2);
  float acc = (v.x - mu) * rr * wv.x * fw.x + (v.y - mu) * rr * wv.y * fw.y;
#pragma unroll
  for (int m = 32; m; m >>= 1) acc += __shfl_xor(acc, m);
  if (l == 0) out[b] = acc + fcb[0];
}

extern "C" void kernel_launch(void* const* d_in, const int* in_sizes, int n_in, void* d_out,
                              int out_size, void* d_ws, size_t ws_size, hipStream_t stream) {
  const float* in_x = (const float*)d_in[0];
  const float* m_ln_w = (const float*)d_in[1];
  const float* m_up_W = (const float*)d_in[2];
  const float* m_conv_W = (const float*)d_in[3];
  const float* m_conv_b = (const float*)d_in[4];
  const float* m_q_W = (const float*)d_in[5];
  const float* m_k_W = (const float*)d_in[6];
  const float* m_v_W = (const float*)d_in[7];
  const float* m_ig_W = (const float*)d_in[8];
  const float* m_ig_b = (const float*)d_in[9];
  const float* m_fg_W = (const float*)d_in[10];
  const float* m_fg_b = (const float*)d_in[11];
  const float* m_on_w = (const float*)d_in[12];
  const float* m_skip = (const float*)d_in[13];
  const float* m_down_W = (const float*)d_in[14];
  const float* s_ln_w = (const float*)d_in[15];
  const float* s_conv_W = (const float*)d_in[16];
  const float* s_conv_b = (const float*)d_in[17];
  const float* s_gates_W = (const float*)d_in[18];
  const float* s_R = (const float*)d_in[19];
  const float* s_bias = (const float*)d_in[20];
  const float* s_gn_w = (const float*)d_in[21];
  const float* s_ffn_ln_w = (const float*)d_in[22];
  const float* s_ffn_up_W = (const float*)d_in[23];
  const float* s_ffn_down_W = (const float*)d_in[24];
  const float* post_norm_w = (const float*)d_in[25];
  const float* fc_W = (const float*)d_in[26];
  const float* fc_b = (const float*)d_in[27];

  float* ws = (float*)d_ws;
  float* X = ws;                    // 1,048,576 floats
  float* UP = X + 1048576;          // 4,194,304
  float* XC = UP + 4194304;         // 2,097,152
  float* Qb = XC + 2097152;         // 2,097,152
  float* Hb = Qb + 2097152;         // 2,097,152
  float* IGb = Hb + 2097152;        // 32,768
  float* FGb = IGb + 32768;         // 32,768
  _Float16* F16 = (_Float16*)(FGb + 32768);
  _Float16* K1 = F16;               // 2,097,152 halfs each
  _Float16* K2 = K1 + 2097152;
  _Float16* V1t = K2 + 2097152;
  _Float16* V2t = V1t + 2097152;

  hipMemcpyAsync(X, in_x, (size_t)BS * E * sizeof(float), hipMemcpyDeviceToDevice, stream);

  int mi = 0;
  for (int blk = 0; blk < 7; blk++) {
    if (blk == 1) {
      slstm_pre_kernel<<<BS, 512, 0, stream>>>(X, s_ln_w, s_conv_W, s_conv_b, s_gates_W,
                                               s_bias, UP);
      slstm_scan9<<<64, 128, 0, stream>>>(UP, s_R, s_gn_w, X);
      gemm3<128, false, 1><<<dim3(6, 128), 256, 0, stream>>>(X, s_ffn_up_W, s_ffn_ln_w, UP,
                                                             384, 128);
      gemm3<192, true, 2><<<dim3(2, 128), 256, 0, stream>>>(UP, s_ffn_down_W, nullptr, X,
                                                            128, 384);
    } else {
      const float* ln_w = m_ln_w + (size_t)mi * E;
      const float* up_W = m_up_W + (size_t)mi * E * 512;
      const float* conv_W = m_conv_W + (size_t)mi * I * 4;
      const float* conv_b = m_conv_b + (size_t)mi * I;
      const float* q_W = m_q_W + (size_t)mi * 1024;
      const float* k_W = m_k_W + (size_t)mi * 1024;
      const float* v_W = m_v_W + (size_t)mi * 1024;
      const float* ig_W = m_ig_W + (size_t)mi * 3072;
      const float* ig_b = m_ig_b + (size_t)mi * 4;
      const float* fg_W = m_fg_W + (size_t)mi * 3072;
      const float* fg_b = m_fg_b + (size_t)mi * 4;
      const float* on_w = m_on_w + (size_t)mi * I;
      const float* skipv = m_skip + (size_t)mi * I;
      const float* down_W = m_down_W + (size_t)mi * I * E;

      gemm3<128, false, 1><<<dim3(8, 128), 256, 0, stream>>>(X, up_W, ln_w, UP, 512, 128);
      mlstm_mid_kernel<<<BS, 256, 0, stream>>>(UP, conv_W, conv_b, q_W, k_W, v_W, ig_W, ig_b,
                                               fg_W, fg_b, XC, Qb, K1, K2, V1t, V2t, IGb,
                                               FGb);
      attn_mfma_kernel<<<512, 256, 0, stream>>>(Qb, K1, K2, V1t, V2t, IGb, FGb, XC, UP, on_w,
                                                skipv, Hb);
      gemm3<256, true, 0><<<dim3(2, 128), 256, 0, stream>>>(Hb, down_W, nullptr, X, 128, 256);
      mi++;
    }
  }
  head_kernel<<<B, 64, 0, stream>>>(X, post_norm_w, fc_W, fc_b, (float*)d_out);
}